// Round 1
// baseline (624.034 us; speedup 1.0000x reference)
//
#include <hip/hip_runtime.h>
#include <math.h>

// StackedLSTM: B=2048, T=2048, D=H=6, 2 layers, softmax(h_last) -> [2048, 6] fp32.
//
// Mapping: wave (64 lanes) = 2 batch slots x 32 lanes.
//   slot s = lane>>5, w = lane&31, layer l = w>>4, q = w&15,
//   unit j = q>>1 (j=6,7 dummy), pair p = q&1 (p=0: i,f rows; p=1: g,o rows).
// Layer 1 runs one timestep behind layer 0 (same instruction stream, disjoint lanes).
// h state lives in per-wave LDS (block = 1 wave -> no barriers, wave-in-order DS).
// x staged 32 steps ahead into LDS (double buffer) to keep HBM latency off the
// recurrence critical path.

#define TSTEPS 2048

__device__ __forceinline__ float fast_rcp(float v) { return __builtin_amdgcn_rcpf(v); }

__global__ __launch_bounds__(64, 1)
void stacked_lstm_kernel(const float* __restrict__ x,
                         const float* __restrict__ Wih0, const float* __restrict__ Whh0,
                         const float* __restrict__ bih0, const float* __restrict__ bhh0,
                         const float* __restrict__ Wih1, const float* __restrict__ Whh1,
                         const float* __restrict__ bih1, const float* __restrict__ bhh1,
                         float* __restrict__ out)
{
    __shared__ __align__(16) float Xs[2][2][192];  // [slot][buf][32 steps * 6]
    __shared__ __align__(16) float Hb[2][2][8];    // [slot][layer][8] (6 used)

    const int lane = threadIdx.x;
    const int s = lane >> 5;          // batch slot within wave
    const int w = lane & 31;
    const int l = w >> 4;             // layer 0/1
    const int q = w & 15;
    const int j = q >> 1;             // unit (0..7; 6,7 dummy)
    const int p = q & 1;              // gate pair: 0 -> (i,f), 1 -> (g,o)
    const bool active = (q < 12);
    const int jc = (j < 6) ? j : 5;
    const long b = (long)blockIdx.x * 2 + s;

    // h(-1) = 0, both layers
    if (w < 16) Hb[s][w >> 3][w & 7] = 0.0f;

    // ---- per-lane weights into VGPRs ----
    const float* Wih = l ? Wih1 : Wih0;
    const float* Whh = l ? Whh1 : Whh0;
    const float* bih = l ? bih1 : bih0;
    const float* bhh = l ? bhh1 : bhh0;
    // PyTorch gate order rows: i=0..5, f=6..11, g=12..17, o=18..23
    const int rA = p * 12 + jc;       // p=0: i-row j ; p=1: g-row j
    const int rB = rA + 6;            // p=0: f-row j ; p=1: o-row j

    float wiA[6], whA[6], wiB[6], whB[6];
#pragma unroll
    for (int k = 0; k < 6; ++k) {
        wiA[k] = Wih[rA * 6 + k];
        whA[k] = Whh[rA * 6 + k];
        wiB[k] = Wih[rB * 6 + k];
        whB[k] = Whh[rB * 6 + k];
    }
    const float bA = bih[rA] + bhh[rA];
    const float bB = bih[rB] + bhh[rB];
    // row A: sigmoid (p=0) or tanh (p=1); row B: always sigmoid.
    // sigmoid(v) = 1 - 1/(1+e^v) ; tanh(v) = 1 - 2/(1+e^{2v})  => scale kA = 1 or 2.
    const float kA = p ? 2.0f : 1.0f;

    // ---- x staging: 32 steps (768 B) per slot, loaded by the 12 layer-0 lanes ----
    const float* xb = x + b * (TSTEPS * 6);
    float4 pre0, pre1, pre2, pre3;

    auto LOADBLK = [&](int blk) {
        if (w < 12) {
            const float4* xv = (const float4*)(xb + blk * 192);
            pre0 = xv[w +  0];
            pre1 = xv[w + 12];
            pre2 = xv[w + 24];
            pre3 = xv[w + 36];
        }
    };
    auto WRITEBLK = [&](int buf) {
        if (w < 12) {
            float4* dst = (float4*)&Xs[s][buf][0];
            dst[w +  0] = pre0;
            dst[w + 12] = pre1;
            dst[w + 24] = pre2;
            dst[w + 36] = pre3;
        }
    };

    LOADBLK(0);
    WRITEBLK(0);      // compiler inserts vmcnt wait for pre*
    LOADBLK(1);       // in flight while block 0 computes
    __builtin_amdgcn_wave_barrier();

    const float* h0p = &Hb[s][0][0];
    const float* h1p = &Hb[s][1][0];

    float c = 0.0f;

    // T+1 iterations: at iter t, layer0 computes step t, layer1 computes step t-1.
    for (int t = 0; t <= TSTEPS; ++t) {
        const int blk = t >> 5;
        const int row = t & 31;
        const int buf = blk & 1;

        if (row == 0 && t > 0) {
            if (blk <= 63) {
                WRITEBLK(blk & 1);
                if (blk + 1 <= 63) LOADBLK(blk + 1);
            }
            __builtin_amdgcn_wave_barrier();
        }
        // t == TSTEPS: blk=64 -> buf=0 holds stale block-62 data; layer0's output
        // at this iter is never consumed, so garbage x is harmless (finite values).

        const float* xr = &Xs[s][buf][row * 6];
        const float* pa = l ? h0p : xr;    // input vec: x_t (L0) or h0 (L1)
        const float* pb = l ? h1p : h0p;   // recurrent h: h0 (L0) or h1 (L1)

        float2 a0 = *(const float2*)(pa + 0);
        float2 a1 = *(const float2*)(pa + 2);
        float2 a2 = *(const float2*)(pa + 4);
        float2 r0 = *(const float2*)(pb + 0);
        float2 r1 = *(const float2*)(pb + 2);
        float2 r2 = *(const float2*)(pb + 4);
        float inp[6] = {a0.x, a0.y, a1.x, a1.y, a2.x, a2.y};
        float hr[6]  = {r0.x, r0.y, r1.x, r1.y, r2.x, r2.y};

        // two gate-row dot products, 4 independent fma chains for ILP
        float sA = bA, sB = bB, tA = 0.0f, tB = 0.0f;
#pragma unroll
        for (int k = 0; k < 6; ++k) {
            sA = fmaf(inp[k], wiA[k], sA);
            sB = fmaf(inp[k], wiB[k], sB);
            tA = fmaf(hr[k],  whA[k], tA);
            tB = fmaf(hr[k],  whB[k], tB);
        }
        sA += tA;
        sB += tB;

        // activations: act = 1 - k * rcp(1 + exp(k*v))
        float eA = __expf(sA * kA);
        float aA = fmaf(kA, -fast_rcp(1.0f + eA), 1.0f);   // p=0: sigmoid(i), p=1: tanh(g)
        float eB = __expf(sB);
        float aB = 1.0f - fast_rcp(1.0f + eB);             // sigmoid (f or o)

        // exchange with pair partner (lane ^ 1)
        float xA = __shfl_xor(aA, 1, 64);
        float xB = __shfl_xor(aB, 1, 64);
        float gi = p ? xA : aA;
        float gf = p ? xB : aB;
        float gg = p ? aA : xA;
        float go = p ? aB : xB;

        float cn = fmaf(gf, c, gi * gg);
        float ec = __expf(cn * 2.0f);
        float th = fmaf(2.0f, -fast_rcp(1.0f + ec), 1.0f); // tanh(cn)
        float hv = go * th;

        // layer1 at t==0 would compute a nonexistent step -1: keep state at 0
        const bool ok = (l == 0) | (t > 0);
        c  = ok ? cn : 0.0f;
        hv = ok ? hv : 0.0f;

        if (active && p == 0) Hb[s][l][jc] = hv;
        __builtin_amdgcn_wave_barrier();
    }

    // ---- epilogue: softmax over Hb[s][1][0..5] (h_last of layer 1) ----
    if (w < 6) {
        const float* hp = &Hb[s][1][0];
        float2 u0 = *(const float2*)(hp + 0);
        float2 u1 = *(const float2*)(hp + 2);
        float2 u2 = *(const float2*)(hp + 4);
        float v0 = u0.x, v1 = u0.y, v2 = u1.x, v3 = u1.y, v4 = u2.x, v5 = u2.y;
        float m = fmaxf(fmaxf(fmaxf(v0, v1), fmaxf(v2, v3)), fmaxf(v4, v5));
        float e0 = __expf(v0 - m), e1 = __expf(v1 - m), e2 = __expf(v2 - m);
        float e3 = __expf(v3 - m), e4 = __expf(v4 - m), e5 = __expf(v5 - m);
        float sum = ((e0 + e1) + (e2 + e3)) + (e4 + e5);
        float r = fast_rcp(sum);
        float mine = (w == 0) ? e0 : (w == 1) ? e1 : (w == 2) ? e2
                   : (w == 3) ? e3 : (w == 4) ? e4 : e5;
        out[b * 6 + w] = mine * r;
    }
}

extern "C" void kernel_launch(void* const* d_in, const int* in_sizes, int n_in,
                              void* d_out, int out_size, void* d_ws, size_t ws_size,
                              hipStream_t stream) {
    (void)in_sizes; (void)n_in; (void)d_ws; (void)ws_size; (void)out_size;
    const float* x    = (const float*)d_in[0];
    const float* Wih0 = (const float*)d_in[1];
    const float* Whh0 = (const float*)d_in[2];
    const float* bih0 = (const float*)d_in[3];
    const float* bhh0 = (const float*)d_in[4];
    const float* Wih1 = (const float*)d_in[5];
    const float* Whh1 = (const float*)d_in[6];
    const float* bih1 = (const float*)d_in[7];
    const float* bhh1 = (const float*)d_in[8];
    float* outp = (float*)d_out;

    // 2048 batch / 2 per wave-block = 1024 blocks of 64 threads
    // = 1024 waves = 1 wave per SIMD machine-wide.
    stacked_lstm_kernel<<<1024, 64, 0, stream>>>(
        x, Wih0, Whh0, bih0, bhh0, Wih1, Whh1, bih1, bhh1, outp);
}

// Round 2
// 535.102 us; speedup vs baseline: 1.1662x; 1.1662x over previous
//
#include <hip/hip_runtime.h>
#include <math.h>

// StackedLSTM: B=2048, T=2048, D=H=6, 2 layers, softmax(h_last) -> [2048, 6] fp32.
//
// Mapping: wave (64 lanes) = 2 batch slots x 32 lanes.
//   slot s = lane>>5, w = lane&31, layer l = w>>4, q = w&15,
//   unit j = q>>1 (j=6,7 dummy), pair p = q&1 (p=0: i,f rows; p=1: g,o rows).
// Layer 1 runs one timestep behind layer 0 (same instruction stream, disjoint lanes).
//
// R2 change vs R1: the recurrence chain no longer touches LDS.
//   - h state stays in the hv VGPR; broadcast via ds_bpermute (crossbar, no
//     write/barrier/read round trip).  R1 spent ~400-500 cyc/step on the LDS
//     h round-trip (550us total, VALUBusy 36%).
//   - pair (i,f)<->(g,o) exchange via DPP quad_perm(1,0,3,2), not ds_swizzle.
//   - exp() pre-multiplies folded into exp2-domain constants.
// x is still staged 32 steps ahead into LDS (double buffer, barrier once per
// 32 steps, off the critical path).

#define TSTEPS 2048

__device__ __forceinline__ float fast_rcp(float v) { return __builtin_amdgcn_rcpf(v); }

__device__ __forceinline__ float bperm_f(int byte_addr, float v) {
    return __int_as_float(__builtin_amdgcn_ds_bpermute(byte_addr, __float_as_int(v)));
}

// lane ^ 1 exchange: quad_perm [1,0,3,2] = 0xB1
__device__ __forceinline__ float dpp_xor1_f(float v) {
    return __int_as_float(__builtin_amdgcn_mov_dpp(__float_as_int(v), 0xB1, 0xF, 0xF, true));
}

#if __has_builtin(__builtin_amdgcn_exp2f)
#define EXP2F(x) __builtin_amdgcn_exp2f(x)
#else
#define EXP2F(x) __expf((x) * 0.69314718056f)
#endif

#define LOG2E 1.442695040889f

__global__ __launch_bounds__(64, 1)
void stacked_lstm_kernel(const float* __restrict__ x,
                         const float* __restrict__ Wih0, const float* __restrict__ Whh0,
                         const float* __restrict__ bih0, const float* __restrict__ bhh0,
                         const float* __restrict__ Wih1, const float* __restrict__ Whh1,
                         const float* __restrict__ bih1, const float* __restrict__ bhh1,
                         float* __restrict__ out)
{
    __shared__ __align__(16) float Xs[2][2][192];  // [slot][buf][32 steps * 6]
    __shared__ __align__(16) float Hb[2][8];       // [slot][8] h1_last for epilogue

    const int lane = threadIdx.x;
    const int s = lane >> 5;          // batch slot within wave
    const int w = lane & 31;
    const int l = w >> 4;             // layer 0/1
    const int q = w & 15;
    const int j = q >> 1;             // unit (0..7; 6,7 dummy)
    const int p = q & 1;              // gate pair: 0 -> (i,f), 1 -> (g,o)
    const int jc = (j < 6) ? j : 5;
    const long b = (long)blockIdx.x * 2 + s;

    // ---- per-lane weights into VGPRs ----
    const float* Wih = l ? Wih1 : Wih0;
    const float* Whh = l ? Whh1 : Whh0;
    const float* bih = l ? bih1 : bih0;
    const float* bhh = l ? bhh1 : bhh0;
    // PyTorch gate order rows: i=0..5, f=6..11, g=12..17, o=18..23
    const int rA = p * 12 + jc;       // p=0: i-row j ; p=1: g-row j
    const int rB = rA + 6;            // p=0: f-row j ; p=1: o-row j

    float wiA[6], whA[6], wiB[6], whB[6];
#pragma unroll
    for (int k = 0; k < 6; ++k) {
        wiA[k] = Wih[rA * 6 + k];
        whA[k] = Whh[rA * 6 + k];
        wiB[k] = Wih[rB * 6 + k];
        whB[k] = Whh[rB * 6 + k];
    }
    const float bA = bih[rA] + bhh[rA];
    const float bB = bih[rB] + bhh[rB];
    // row A: sigmoid (p=0) or tanh (p=1); row B: always sigmoid.
    // sigmoid(v) = 1 - 1/(1+e^v) ; tanh(v) = 1 - 2/(1+e^{2v})  => scale kA = 1 or 2.
    const float kA  = p ? 2.0f : 1.0f;
    const float kAl = p ? (2.0f * LOG2E) : LOG2E;   // exp2-domain premultiply

    // ---- x staging: 32 steps (768 B) per slot, loaded by the 12 layer-0 lanes ----
    const float* xb = x + b * (TSTEPS * 6);
    float4 pre0, pre1, pre2, pre3;

    auto LOADBLK = [&](int blk) {
        if (w < 12) {
            const float4* xv = (const float4*)(xb + blk * 192);
            pre0 = xv[w +  0];
            pre1 = xv[w + 12];
            pre2 = xv[w + 24];
            pre3 = xv[w + 36];
        }
    };
    auto WRITEBLK = [&](int buf) {
        if (w < 12) {
            float4* dst = (float4*)&Xs[s][buf][0];
            dst[w +  0] = pre0;
            dst[w + 12] = pre1;
            dst[w + 24] = pre2;
            dst[w + 36] = pre3;
        }
    };

    LOADBLK(0);
    WRITEBLK(0);
    LOADBLK(1);
    __builtin_amdgcn_wave_barrier();

    // bpermute byte addresses (loop-invariant):
    //   hr[k]  <- lane s*32 + l*16 + 2k   (own layer's h)
    //   pa[k]  <- lane s*32 + 2k          (layer0 h, used by layer1 lanes)
    const int base_hr = ((s << 5) + (l << 4)) << 2;
    const int base_pa = (s << 5) << 2;

    float hv = 0.0f;   // own h (valid on all lanes; sourced from p=0 lanes)
    float c  = 0.0f;

    // T+1 iterations: at iter t, layer0 computes step t, layer1 computes step t-1.
    for (int t = 0; t <= TSTEPS; ++t) {
        const int blk = t >> 5;
        const int row = t & 31;
        const int buf = blk & 1;

        if (row == 0 && t > 0) {
            if (blk <= 63) {
                WRITEBLK(blk & 1);
                if (blk + 1 <= 63) LOADBLK(blk + 1);
            }
            __builtin_amdgcn_wave_barrier();
        }
        // t == TSTEPS: layer0 reads stale x; its output is never consumed.

        const float* xr = &Xs[s][buf][row * 6];
        float2 a0 = *(const float2*)(xr + 0);
        float2 a1 = *(const float2*)(xr + 2);
        float2 a2 = *(const float2*)(xr + 4);
        float xv6[6] = {a0.x, a0.y, a1.x, a1.y, a2.x, a2.y};

        // broadcast previous-step h via crossbar (12 independent ops, pipelined)
        float hr[6], pa[6];
#pragma unroll
        for (int k = 0; k < 6; ++k) hr[k] = bperm_f(base_hr + 8 * k, hv);
#pragma unroll
        for (int k = 0; k < 6; ++k) pa[k] = bperm_f(base_pa + 8 * k, hv);

        float vA[6];
#pragma unroll
        for (int k = 0; k < 6; ++k) vA[k] = l ? pa[k] : xv6[k];

        // two gate-row dot products, 4 independent fma chains
        float sA = bA, sB = bB, tA = 0.0f, tB = 0.0f;
#pragma unroll
        for (int k = 0; k < 6; ++k) {
            sA = fmaf(vA[k], wiA[k], sA);
            sB = fmaf(vA[k], wiB[k], sB);
            tA = fmaf(hr[k],  whA[k], tA);
            tB = fmaf(hr[k],  whB[k], tB);
        }
        sA += tA;
        sB += tB;

        // activations: act = 1 - k * rcp(1 + exp2(k*log2e*v))
        float eA = EXP2F(sA * kAl);
        float aA = fmaf(kA, -fast_rcp(1.0f + eA), 1.0f);   // p=0: sigmoid(i), p=1: tanh(g)
        float eB = EXP2F(sB * LOG2E);
        float aB = 1.0f - fast_rcp(1.0f + eB);             // sigmoid (f or o)

        // pair exchange (lane^1) via DPP, then assemble cell update
        float xA = dpp_xor1_f(aA);
        float xB = dpp_xor1_f(aB);
        float ig = aA * xA;                 // i*g on both pair lanes
        float gf = p ? xB : aB;             // forget gate
        float go = p ? aB : xB;             // output gate

        float cn = fmaf(gf, c, ig);
        float ec = EXP2F(cn * (2.0f * LOG2E));
        float th = fmaf(2.0f, -fast_rcp(1.0f + ec), 1.0f); // tanh(cn)
        float hn = go * th;

        // layer1 at t==0 computes a nonexistent step: keep its state at 0
        const bool ok = (l == 0) | (t > 0);
        c  = ok ? cn : 0.0f;
        hv = ok ? hn : 0.0f;
    }

    // ---- epilogue: hv on layer-1 lanes is h1(T-1); softmax over it ----
    if (l == 1 && p == 0 && j < 6) Hb[s][j] = hv;
    __builtin_amdgcn_wave_barrier();

    if (w < 6) {
        const float* hp = &Hb[s][0];
        float2 u0 = *(const float2*)(hp + 0);
        float2 u1 = *(const float2*)(hp + 2);
        float2 u2 = *(const float2*)(hp + 4);
        float v0 = u0.x, v1 = u0.y, v2 = u1.x, v3 = u1.y, v4 = u2.x, v5 = u2.y;
        float m = fmaxf(fmaxf(fmaxf(v0, v1), fmaxf(v2, v3)), fmaxf(v4, v5));
        float e0 = __expf(v0 - m), e1 = __expf(v1 - m), e2 = __expf(v2 - m);
        float e3 = __expf(v3 - m), e4 = __expf(v4 - m), e5 = __expf(v5 - m);
        float sum = ((e0 + e1) + (e2 + e3)) + (e4 + e5);
        float r = fast_rcp(sum);
        float mine = (w == 0) ? e0 : (w == 1) ? e1 : (w == 2) ? e2
                   : (w == 3) ? e3 : (w == 4) ? e4 : e5;
        out[b * 6 + w] = mine * r;
    }
}

extern "C" void kernel_launch(void* const* d_in, const int* in_sizes, int n_in,
                              void* d_out, int out_size, void* d_ws, size_t ws_size,
                              hipStream_t stream) {
    (void)in_sizes; (void)n_in; (void)d_ws; (void)ws_size; (void)out_size;
    const float* x    = (const float*)d_in[0];
    const float* Wih0 = (const float*)d_in[1];
    const float* Whh0 = (const float*)d_in[2];
    const float* bih0 = (const float*)d_in[3];
    const float* bhh0 = (const float*)d_in[4];
    const float* Wih1 = (const float*)d_in[5];
    const float* Whh1 = (const float*)d_in[6];
    const float* bih1 = (const float*)d_in[7];
    const float* bhh1 = (const float*)d_in[8];
    float* outp = (float*)d_out;

    // 2048 batch / 2 per wave = 1024 blocks of 64 threads
    // = 1024 waves = 1 wave per SIMD machine-wide.
    stacked_lstm_kernel<<<1024, 64, 0, stream>>>(
        x, Wih0, Whh0, bih0, bhh0, Wih1, Whh1, bih1, bhh1, outp);
}